// Round 2
// baseline (182.797 us; speedup 1.0000x reference)
//
#include <hip/hip_runtime.h>
#include <cstdint>
#include <cstddef>

// GRU cell fused: B=16384, I=H=512.
// ws layout: X bf16 [16384][1024] (input|hidden)  @0,        33554432 B
//            Wrz bf16 [1024][1024] (=W_gate)      @33554432,  2097152 B
//            Wih bf16 [512][1024] (W_i|W_h)       @35651584,  1048576 B

typedef __attribute__((ext_vector_type(8))) __bf16 bf16x8;
typedef __attribute__((ext_vector_type(4))) float f32x4;
typedef __attribute__((ext_vector_type(8))) unsigned short u16x8;

__device__ __forceinline__ unsigned short f2bf(float f) {
    unsigned u = __builtin_bit_cast(unsigned, f);
    return (unsigned short)((u + 0x7fffu + ((u >> 16) & 1u)) >> 16);  // RNE
}

__global__ void prep_x(const float* __restrict__ inp, const float* __restrict__ hid,
                       unsigned short* __restrict__ X) {
    int t = blockIdx.x * 256 + threadIdx.x;   // 16384*128 threads
    int b = t >> 7;
    int j = (t & 127) << 3;                   // 0..1016, step 8
    const float* src = (j < 512) ? (inp + (size_t)b * 512 + j)
                                 : (hid + (size_t)b * 512 + (j - 512));
    u16x8 o;
#pragma unroll
    for (int e = 0; e < 8; ++e) o[e] = f2bf(src[e]);
    *reinterpret_cast<u16x8*>(X + (size_t)b * 1024 + j) = o;
}

__global__ void prep_w(const float* __restrict__ Wg, const float* __restrict__ Wi,
                       const float* __restrict__ Wh,
                       unsigned short* __restrict__ Wrz, unsigned short* __restrict__ Wih) {
    int t = blockIdx.x * 256 + threadIdx.x;   // 196608 threads
    if (t < 131072) {                         // W_gate: 1M elements, 8/thread
        const float* src = Wg + (size_t)t * 8;
        u16x8 o;
#pragma unroll
        for (int e = 0; e < 8; ++e) o[e] = f2bf(src[e]);
        *reinterpret_cast<u16x8*>(Wrz + (size_t)t * 8) = o;
    } else {                                  // Wih[n][k] = k<512 ? Wi[n][k] : Wh[n][k-512]
        int u = t - 131072;                   // 65536 threads: 512 rows x 128 chunks
        int n = u >> 7;                       // 0..511
        int k = (u & 127) << 3;               // 0..1016
        const float* src = (k < 512) ? (Wi + (size_t)n * 512 + k)
                                     : (Wh + (size_t)n * 512 + (k - 512));
        u16x8 o;
#pragma unroll
        for (int e = 0; e < 8; ++e) o[e] = f2bf(src[e]);
        *reinterpret_cast<u16x8*>(Wih + (size_t)n * 1024 + k) = o;
    }
}

__device__ __forceinline__ void gload16(const void* g, void* l) {
    __builtin_amdgcn_global_load_lds(
        (const __attribute__((address_space(1))) void*)g,
        (__attribute__((address_space(3))) void*)l, 16, 0, 0);
}

// LDS tile: 64 rows x 64 bf16 (128 B/row), XOR-swizzled: logical chunk ch (16B units)
// of row r is stored at chunk (ch ^ (r&7)).  Staged via pre-swizzled global source.
__device__ __forceinline__ bf16x8 ldfrag(const unsigned short* base, int row, int ch) {
    const char* p = (const char*)base + row * 128 + ((ch ^ (row & 7)) << 4);
    return *reinterpret_cast<const bf16x8*>(p);
}

__global__ __launch_bounds__(256, 2) void gru_fused(
        const unsigned short* __restrict__ X,    // [16384][1024]
        const unsigned short* __restrict__ Wr,   // [512][1024]
        const unsigned short* __restrict__ Wz,   // [512][1024]
        const unsigned short* __restrict__ Wih,  // [512][1024]
        const float* __restrict__ hidden,        // [16384][512]
        const float* __restrict__ bgate,         // [1024]
        const float* __restrict__ bi,            // [512]
        const float* __restrict__ bh,            // [512]
        float* __restrict__ out) {               // [16384][512]
    __shared__ unsigned short lX[64 * 64];
    __shared__ unsigned short lR[64 * 64];
    __shared__ unsigned short lZ[64 * 64];
    __shared__ unsigned short lW[64 * 64];

    const int tid = threadIdx.x;
    const int lane = tid & 63;
    const int wid = tid >> 6;
    const int wm = wid >> 1, wn = wid & 1;      // 2x2 waves, 32x32 per gate each
    const int bid = blockIdx.x;
    const int bn = bid & 7;                     // 8 col tiles -> round-robin to 8 XCDs
    const int bm = bid >> 3;                    // 256 row tiles

    // --- staging addressing (2 chunks of 16B per thread per tile) ---
    const int rowa = tid >> 3;                  // 0..31 (chunk row), second chunk row+32
    const int lc   = (tid & 7) ^ (rowa & 7);    // pre-swizzled logical chunk col
    const size_t xbase = ((size_t)(bm * 64 + rowa) * 1024 + lc * 8) * 2;
    const size_t wbase = ((size_t)(bn * 64 + rowa) * 1024 + lc * 8) * 2;
    const char* gX0 = (const char*)X   + xbase; const char* gX1 = gX0 + 32 * 2048;
    const char* gR0 = (const char*)Wr  + wbase; const char* gR1 = gR0 + 32 * 2048;
    const char* gZ0 = (const char*)Wz  + wbase; const char* gZ1 = gZ0 + 32 * 2048;
    const char* gW0 = (const char*)Wih + wbase; const char* gW1 = gW0 + 32 * 2048;
    char* lX0 = (char*)lX + tid * 16; char* lX1 = lX0 + 4096;
    char* lR0 = (char*)lR + tid * 16; char* lR1 = lR0 + 4096;
    char* lZ0 = (char*)lZ + tid * 16; char* lZ1 = lZ0 + 4096;
    char* lW0 = (char*)lW + tid * 16; char* lW1 = lW0 + 4096;

    f32x4 accR[2][2] = {{{0.f,0.f,0.f,0.f},{0.f,0.f,0.f,0.f}},{{0.f,0.f,0.f,0.f},{0.f,0.f,0.f,0.f}}};
    f32x4 accZ[2][2] = {{{0.f,0.f,0.f,0.f},{0.f,0.f,0.f,0.f}},{{0.f,0.f,0.f,0.f},{0.f,0.f,0.f,0.f}}};
    f32x4 accI[2][2] = {{{0.f,0.f,0.f,0.f},{0.f,0.f,0.f,0.f}},{{0.f,0.f,0.f,0.f},{0.f,0.f,0.f,0.f}}};
    f32x4 accH[2][2] = {{{0.f,0.f,0.f,0.f},{0.f,0.f,0.f,0.f}},{{0.f,0.f,0.f,0.f},{0.f,0.f,0.f,0.f}}};

    const int ra = wm * 32 + (lane & 15);       // A-frag row (X row in tile)
    const int rb = wn * 32 + (lane & 15);       // B-frag row (W row = out col in tile)
    const int c0 = lane >> 4;                   // 0..3, k-chunk within 32

#define MFMA4(ACC, A0, A1, B0, B1)                                                    \
    ACC[0][0] = __builtin_amdgcn_mfma_f32_16x16x32_bf16(A0, B0, ACC[0][0], 0, 0, 0); \
    ACC[1][0] = __builtin_amdgcn_mfma_f32_16x16x32_bf16(A1, B0, ACC[1][0], 0, 0, 0); \
    ACC[0][1] = __builtin_amdgcn_mfma_f32_16x16x32_bf16(A0, B1, ACC[0][1], 0, 0, 0); \
    ACC[1][1] = __builtin_amdgcn_mfma_f32_16x16x32_bf16(A1, B1, ACC[1][1], 0, 0, 0);

#define KSTEP(kt, ACC3)                                                    \
    {                                                                      \
        gload16(gX0 + (kt) * 128, lX0); gload16(gX1 + (kt) * 128, lX1);    \
        gload16(gR0 + (kt) * 128, lR0); gload16(gR1 + (kt) * 128, lR1);    \
        gload16(gZ0 + (kt) * 128, lZ0); gload16(gZ1 + (kt) * 128, lZ1);    \
        gload16(gW0 + (kt) * 128, lW0); gload16(gW1 + (kt) * 128, lW1);    \
        __syncthreads();                                                   \
        _Pragma("unroll")                                                  \
        for (int ks = 0; ks < 2; ++ks) {                                   \
            const int ch = ks * 4 + c0;                                    \
            bf16x8 a0 = ldfrag(lX, ra, ch);                                \
            bf16x8 a1 = ldfrag(lX, ra + 16, ch);                           \
            bf16x8 b0 = ldfrag(lR, rb, ch);                                \
            bf16x8 b1 = ldfrag(lR, rb + 16, ch);                           \
            MFMA4(accR, a0, a1, b0, b1)                                    \
            b0 = ldfrag(lZ, rb, ch);                                       \
            b1 = ldfrag(lZ, rb + 16, ch);                                  \
            MFMA4(accZ, a0, a1, b0, b1)                                    \
            b0 = ldfrag(lW, rb, ch);                                       \
            b1 = ldfrag(lW, rb + 16, ch);                                  \
            MFMA4(ACC3, a0, a1, b0, b1)                                    \
        }                                                                  \
        __syncthreads();                                                   \
    }

    for (int kt = 0; kt < 8; ++kt) KSTEP(kt, accI)    // k in [0,512): input part -> i_gate
    for (int kt = 8; kt < 16; ++kt) KSTEP(kt, accH)   // k in [512,1024): hidden part -> h_gate
#undef KSTEP
#undef MFMA4

    // --- fused GRU epilogue ---
    const int colb = bn * 64 + wn * 32 + (lane & 15);
    const int rowb = bm * 64 + wm * 32 + ((lane >> 4) << 2);
#pragma unroll
    for (int ni = 0; ni < 2; ++ni) {
        const int n = colb + ni * 16;
        const float bgr = bgate[n];
        const float bgz = bgate[512 + n];
        const float bii = bi[n];
        const float bhh = bh[n];
#pragma unroll
        for (int mi = 0; mi < 2; ++mi) {
#pragma unroll
            for (int r = 0; r < 4; ++r) {
                const int m = rowb + mi * 16 + r;
                const size_t off = (size_t)m * 512 + n;
                float rg = accR[mi][ni][r] + bgr;
                rg = 1.f / (1.f + __expf(-rg));
                float zg = accZ[mi][ni][r] + bgz;
                zg = 1.f / (1.f + __expf(-zg));
                float x = accI[mi][ni][r] + bii + rg * (accH[mi][ni][r] + bhh);
                x = fminf(fmaxf(x, -15.f), 15.f);
                const float e = __expf(2.f * x);
                const float ng = (e - 1.f) / (e + 1.f);   // tanh(x)
                out[off] = ng + zg * (hidden[off] - ng);  // (1-z)*n + z*h
            }
        }
    }
}

extern "C" void kernel_launch(void* const* d_in, const int* in_sizes, int n_in,
                              void* d_out, int out_size, void* d_ws, size_t ws_size,
                              hipStream_t stream) {
    const float* inp = (const float*)d_in[0];
    const float* hid = (const float*)d_in[1];
    const float* Wg  = (const float*)d_in[2];
    const float* bg  = (const float*)d_in[3];
    const float* Wi  = (const float*)d_in[4];
    const float* bi  = (const float*)d_in[5];
    const float* Wh  = (const float*)d_in[6];
    const float* bh  = (const float*)d_in[7];
    float* out = (float*)d_out;

    unsigned short* X   = (unsigned short*)d_ws;
    unsigned short* Wrz = (unsigned short*)((char*)d_ws + 33554432);
    unsigned short* Wih = (unsigned short*)((char*)d_ws + 33554432 + 2097152);

    prep_x<<<8192, 256, 0, stream>>>(inp, hid, X);
    prep_w<<<768, 256, 0, stream>>>(Wg, Wi, Wh, Wrz, Wih);
    gru_fused<<<2048, 256, 0, stream>>>(X, Wrz, Wrz + 512 * 1024, Wih, hid, bg, bi, bh, out);
}